// Round 13
// baseline (277.063 us; speedup 1.0000x reference)
//
#include <hip/hip_runtime.h>
#include <hip/hip_bf16.h>

#define N_NODES 50000
#define N_EDGES 800000
#define MP 50048  // N_NODES padded to multiple of 64
#define NB 98     // dst buckets of 512 nodes (50000 >> 9 -> 98)
#define BSH 9

typedef unsigned short ushort_t;
typedef unsigned int uint_t;
typedef __attribute__((ext_vector_type(8))) __bf16 bf16x8;
typedef __attribute__((ext_vector_type(4))) float f32x4;
typedef __attribute__((ext_vector_type(2))) float f32x2;

__device__ __forceinline__ float bf2f(uint_t u) {
    union { uint_t i; float f; } v; v.i = u << 16; return v.f;
}
__device__ __forceinline__ ushort_t f2bf(float f) {
    union { float f; uint_t i; } v; v.f = f;
    uint_t u = v.i;
    return (ushort_t)((u + 0x7FFFu + ((u >> 16) & 1u)) >> 16);
}
// accumulate 8 fp8 (e4m3) values held in a uint2
__device__ __forceinline__ void accf8(float* a, uint2 d) {
    f32x2 p;
    p = __builtin_amdgcn_cvt_pk_f32_fp8(d.x, false); a[0] += p.x; a[1] += p.y;
    p = __builtin_amdgcn_cvt_pk_f32_fp8(d.x, true);  a[2] += p.x; a[3] += p.y;
    p = __builtin_amdgcn_cvt_pk_f32_fp8(d.y, false); a[4] += p.x; a[5] += p.y;
    p = __builtin_amdgcn_cvt_pk_f32_fp8(d.y, true);  a[6] += p.x; a[7] += p.y;
}
// pack high halves of two f32 -> two bf16 (truncation)
__device__ __forceinline__ uint_t pk_hi(float a, float b) {
    return __builtin_amdgcn_perm(__float_as_uint(b), __float_as_uint(a), 0x07060302);
}

// ---------------- CSR build ----------------
__global__ void deg_k(const int* __restrict__ dst, int* __restrict__ deg, int E) {
    int e = blockIdx.x * 256 + threadIdx.x;
    if (e < E) atomicAdd(&deg[dst[e]], 1);
}

__global__ void scan1_k(const int* __restrict__ deg, int* __restrict__ offs,
                        int* __restrict__ bsum, int n) {
    __shared__ int s[256];
    int i = blockIdx.x * 256 + threadIdx.x;
    int v = (i < n) ? deg[i] : 0;
    s[threadIdx.x] = v;
    __syncthreads();
    #pragma unroll
    for (int d = 1; d < 256; d <<= 1) {
        int t = (threadIdx.x >= d) ? s[threadIdx.x - d] : 0;
        __syncthreads();
        s[threadIdx.x] += t;
        __syncthreads();
    }
    if (i < n) offs[i] = s[threadIdx.x] - v;   // exclusive
    if (threadIdx.x == 255) bsum[blockIdx.x] = s[255];
}

__global__ void scan2_k(int* __restrict__ bsum, int nb) {  // single block
    __shared__ int s[256];
    int v = (threadIdx.x < nb) ? bsum[threadIdx.x] : 0;
    s[threadIdx.x] = v;
    __syncthreads();
    #pragma unroll
    for (int d = 1; d < 256; d <<= 1) {
        int t = (threadIdx.x >= d) ? s[threadIdx.x - d] : 0;
        __syncthreads();
        s[threadIdx.x] += t;
        __syncthreads();
    }
    if (threadIdx.x < nb) bsum[threadIdx.x] = s[threadIdx.x] - v;  // exclusive
}

__global__ void scan3_k(int* __restrict__ offs, const int* __restrict__ bsum,
                        int* __restrict__ bcur, int n, int E) {
    int i = blockIdx.x * 256 + threadIdx.x;
    if (i < n) {
        int v = offs[i] + bsum[blockIdx.x];
        offs[i] = v;
        if ((i & 511) == 0) bcur[i >> BSH] = v;   // bucket append cursors = offs[b<<9]
    }
    if (i == 0) offs[n] = E;
}

// ---- Phase A: bin edges by dst>>9 into ebuf (u32 = dst<<16 | src), grouped writes ----
__global__ __launch_bounds__(256) void binA_k(const int* __restrict__ src,
                                              const int* __restrict__ dst,
                                              int* __restrict__ bcur,
                                              uint_t* __restrict__ ebuf, int E) {
    __shared__ int cnt[NB];
    __shared__ int base[NB];
    int t = threadIdx.x;
    if (t < NB) cnt[t] = 0;
    __syncthreads();
    int myE = blockIdx.x * 2048 + t * 8;
    uint_t pk[8];
    int bk[8];
    int nval = 0;
    if (myE + 8 <= E) {
        int4 d0 = *reinterpret_cast<const int4*>(dst + myE);
        int4 d1 = *reinterpret_cast<const int4*>(dst + myE + 4);
        int4 s0 = *reinterpret_cast<const int4*>(src + myE);
        int4 s1 = *reinterpret_cast<const int4*>(src + myE + 4);
        int dd[8] = {d0.x, d0.y, d0.z, d0.w, d1.x, d1.y, d1.z, d1.w};
        int ss[8] = {s0.x, s0.y, s0.z, s0.w, s1.x, s1.y, s1.z, s1.w};
        nval = 8;
        #pragma unroll
        for (int i = 0; i < 8; ++i) {
            pk[i] = ((uint_t)dd[i] << 16) | (uint_t)ss[i];
            bk[i] = dd[i] >> BSH;
            atomicAdd(&cnt[bk[i]], 1);
        }
    } else {
        for (int e = myE; e < E && nval < 8; ++e) {
            int d = dst[e];
            pk[nval] = ((uint_t)d << 16) | (uint_t)src[e];
            bk[nval] = d >> BSH;
            atomicAdd(&cnt[bk[nval]], 1);
            ++nval;
        }
    }
    __syncthreads();
    if (t < NB) {
        int c = cnt[t];
        base[t] = c ? atomicAdd(&bcur[t], c) : 0;
        cnt[t] = 0;
    }
    __syncthreads();
    for (int i = 0; i < nval; ++i) {
        int r = atomicAdd(&cnt[bk[i]], 1);
        ebuf[base[bk[i]] + r] = pk[i];
    }
}

// ---- Phase B: per bucket, LDS-sort to exact per-node order, coalesced csrc write ----
__global__ __launch_bounds__(256) void binB_k(const uint_t* __restrict__ ebuf,
                                              const int* __restrict__ offs,
                                              ushort_t* __restrict__ csrc) {
    __shared__ int lcur[512];
    __shared__ ushort_t lsrc[10240];   // mean 8192 edges/bucket + 22 sigma headroom
    int b = blockIdx.x;
    int n0 = b << BSH;
    int n1 = min(n0 + 512, N_NODES);
    int t = threadIdx.x;
    int obase = offs[n0];
    int cntE = offs[n1] - obase;
    for (int i = t; i < n1 - n0; i += 256) lcur[i] = offs[n0 + i] - obase;
    __syncthreads();
    for (int i = t; i < cntE; i += 256) {
        uint_t pk = ebuf[obase + i];
        int d = (int)(pk >> 16) - n0;
        int p = atomicAdd(&lcur[d], 1);
        lsrc[p] = (ushort_t)(pk & 0xffffu);
    }
    __syncthreads();
    for (int i = t; i < cntE; i += 256) csrc[obase + i] = lsrc[i];
}

// ---------------- fused weight packing (all 3 layers) + dcnt zeroing ----------------
__device__ __forceinline__ void pack_one(const float* Wl, const float* Wr,
                                         ushort_t* P, int K, int F, int t) {
    int NOUT = 2 * F;
    int lane = t & 63;
    int frag = t >> 6;
    int nct = NOUT / 16;
    int ct = frag % nct;
    int kt = frag / nct;
    int col = ct * 16 + (lane & 15);
    const float* W = (col < F) ? Wl : Wr;
    int c = (col < F) ? col : col - F;
    int k0 = kt * 32 + (lane >> 4) * 8;
    uint_t w[4];
    #pragma unroll
    for (int p = 0; p < 4; ++p) {
        ushort_t lo = f2bf(W[(size_t)(k0 + 2 * p) * F + c]);
        ushort_t hi = f2bf(W[(size_t)(k0 + 2 * p + 1) * F + c]);
        w[p] = (uint_t)lo | ((uint_t)hi << 16);
    }
    *(reinterpret_cast<uint4*>(P) + t) = make_uint4(w[0], w[1], w[2], w[3]);
}

__global__ void pack_all_k(const float* __restrict__ W1l, const float* __restrict__ W1r,
                           const float* __restrict__ W2l, const float* __restrict__ W2r,
                           const float* __restrict__ W3l, const float* __restrict__ W3r,
                           ushort_t* __restrict__ pB1, ushort_t* __restrict__ pB2,
                           ushort_t* __restrict__ pB3, int* __restrict__ dcnt) {
    int tid = blockIdx.x * 256 + threadIdx.x;
    if (tid < 16384)       pack_one(W1l, W1r, pB1, 256, 256, tid);
    else if (tid < 24576)  pack_one(W2l, W2r, pB2, 256, 128, tid - 16384);
    else if (tid < 26624)  pack_one(W3l, W3r, pB3, 128, 64, tid - 24576);
    else {
        int z = tid - 26624;                     // zero dcnt: 50000 ints as uint4
        if (z < 12500)
            *(reinterpret_cast<uint4*>(dcnt) + z) = make_uint4(0, 0, 0, 0);
    }
}

// ---------------- GEMM: B slice (CTW=2) truly in VGPRs + double-buffered A staging ----------------
// NCB=128 cols/block -> per-wave breg = KT*2 frags (<=64 VGPR) -> resident at
// launch_bounds(256,3). Block grid-strides over 32-row tiles; inner loop is
// ds_read + MFMA only. Weight frag as MFMA A-operand -> thread holds 4
// consecutive output cols of one row -> packed u32 (4xfp8)/uint2 (4xbf16) stores.
template <int K, int NOUT, int NCB, int PF, bool F32A, int BPG>
__global__ __launch_bounds__(256, 3) void gemm_k(
    const void* __restrict__ Av, const ushort_t* __restrict__ Bp,
    unsigned char* __restrict__ Pout, ushort_t* __restrict__ Rout, int nvalid) {
    constexpr int KT = K / 32;
    constexpr int CTW = NCB / 64;     // col-tiles per wave (= 2)
    constexpr int NCG = NOUT / NCB;   // col groups (separate blocks)
    constexpr int RS = NOUT - PF;     // R row stride
    constexpr int PADE = K + 8;
    constexpr int NTILES = MP / 32;   // 1564
    constexpr int NWR = K / 64;       // 16B LDS chunks per thread in staging
    __shared__ ushort_t Atile[32 * PADE];

    int cg = (NCG > 1) ? ((int)blockIdx.x % NCG) : 0;
    int bid = (NCG > 1) ? ((int)blockIdx.x / NCG) : (int)blockIdx.x;
    int wave = threadIdx.x >> 6;
    int lane = threadIdx.x & 63;
    int ct0 = cg * (NCB / 16) + wave * CTW;

    bf16x8 breg[KT][CTW];
    #pragma unroll
    for (int kt = 0; kt < KT; ++kt)
        #pragma unroll
        for (int ct = 0; ct < CTW; ++ct)
            breg[kt][ct] = *reinterpret_cast<const bf16x8*>(
                Bp + ((size_t)(kt * (NOUT / 16) + ct0 + ct) * 64 + lane) * 8);

    int arowoff = lane & 15;
    int r0 = (lane >> 4) * 4;
    int srow = threadIdx.x >> 3;
    int sel = (threadIdx.x & 7) * (K / 8);

    float4 fr[2 * NWR];
    uint4 ur[NWR];

    auto loadregs = [&](int t) {
        int grow = min(t * 32 + srow, nvalid - 1);
        if (F32A) {
            const float* A = (const float*)Av + (size_t)grow * K + sel;
            #pragma unroll
            for (int i = 0; i < NWR; ++i) {
                fr[2 * i]     = *reinterpret_cast<const float4*>(A + i * 8);
                fr[2 * i + 1] = *reinterpret_cast<const float4*>(A + i * 8 + 4);
            }
        } else {
            const ushort_t* A = (const ushort_t*)Av + (size_t)grow * K + sel;
            #pragma unroll
            for (int i = 0; i < NWR; ++i)
                ur[i] = *reinterpret_cast<const uint4*>(A + i * 8);
        }
    };
    auto writelds = [&]() {
        ushort_t* dst = &Atile[srow * PADE + sel];
        if (F32A) {
            #pragma unroll
            for (int i = 0; i < NWR; ++i) {
                uint4 w;
                w.x = pk_hi(fr[2 * i].x, fr[2 * i].y);
                w.y = pk_hi(fr[2 * i].z, fr[2 * i].w);
                w.z = pk_hi(fr[2 * i + 1].x, fr[2 * i + 1].y);
                w.w = pk_hi(fr[2 * i + 1].z, fr[2 * i + 1].w);
                *reinterpret_cast<uint4*>(dst + i * 8) = w;
            }
        } else {
            #pragma unroll
            for (int i = 0; i < NWR; ++i)
                *reinterpret_cast<uint4*>(dst + i * 8) = ur[i];
        }
    };

    loadregs(bid);
    writelds();

    for (int t = bid; t < NTILES; t += BPG) {
        __syncthreads();
        int tn = t + BPG;
        if (tn < NTILES) loadregs(tn);

        f32x4 acc[2][CTW];
        #pragma unroll
        for (int r = 0; r < 2; ++r)
            #pragma unroll
            for (int c = 0; c < CTW; ++c) acc[r][c] = (f32x4){0.f, 0.f, 0.f, 0.f};

        const ushort_t* A0 = &Atile[arowoff * PADE + (lane >> 4) * 8];
        #pragma unroll
        for (int kt = 0; kt < KT; ++kt) {
            bf16x8 x0 = *reinterpret_cast<const bf16x8*>(A0 + kt * 32);
            bf16x8 x1 = *reinterpret_cast<const bf16x8*>(A0 + 16 * PADE + kt * 32);
            #pragma unroll
            for (int ct = 0; ct < CTW; ++ct) {
                acc[0][ct] = __builtin_amdgcn_mfma_f32_16x16x32_bf16(breg[kt][ct], x0, acc[0][ct], 0, 0, 0);
                acc[1][ct] = __builtin_amdgcn_mfma_f32_16x16x32_bf16(breg[kt][ct], x1, acc[1][ct], 0, 0, 0);
            }
        }

        int rowBase = t * 32;
        #pragma unroll
        for (int r = 0; r < 2; ++r) {
            int xrow = rowBase + r * 16 + arowoff;
            #pragma unroll
            for (int ct = 0; ct < CTW; ++ct) {
                int wc = (ct0 + ct) * 16 + r0;
                f32x4 v = acc[r][ct];
                if (PF > 0 && wc < PF) {
                    uint_t u = __builtin_amdgcn_cvt_pk_fp8_f32(v[0], v[1], 0u, false);
                    u = __builtin_amdgcn_cvt_pk_fp8_f32(v[2], v[3], u, true);
                    *reinterpret_cast<uint_t*>(Pout + (size_t)xrow * PF + wc) = u;
                } else {
                    uint2 w;
                    w.x = (uint_t)f2bf(v[0]) | ((uint_t)f2bf(v[1]) << 16);
                    w.y = (uint_t)f2bf(v[2]) | ((uint_t)f2bf(v[3]) << 16);
                    *reinterpret_cast<uint2*>(Rout + (size_t)xrow * RS + (wc - PF)) = w;
                }
            }
        }

        __syncthreads();
        if (tn < NTILES) writelds();
    }
}

// ---------------- fused aggregate (fp8 P) + epilogue, 2 nodes/wave ----------------
template <int F, bool FINAL>
__global__ __launch_bounds__(256) void aggP8_k(
    const unsigned char* __restrict__ P, const int* __restrict__ offs,
    const ushort_t* __restrict__ csrc, const ushort_t* __restrict__ R,
    const float* __restrict__ bias, ushort_t* __restrict__ H,
    float* __restrict__ hout, float* __restrict__ lout, int n) {
    constexpr int LPG = F / 8;
    constexpr int G = 64 / LPG;
    constexpr int U = (G >= 4) ? 1 : (4 / G);
    constexpr int ST = G * U;
    int wid = (blockIdx.x * 256 + threadIdx.x) >> 6;
    int lane = threadIdx.x & 63;
    int g = lane / LPG;
    int sub = lane & (LPG - 1);
    int colbase = sub * 8;
    int n0 = 2 * wid, n1 = 2 * wid + 1;
    if (n0 >= n) return;
    bool has1 = (n1 < n);
    int b0 = offs[n0], end0 = offs[n0 + 1];
    int b1 = has1 ? offs[n1] : 0, end1 = has1 ? offs[n1 + 1] : 0;

    float a0[8] = {0,0,0,0,0,0,0,0};
    float a1[8] = {0,0,0,0,0,0,0,0};
    int e0 = b0, e1 = b1;
    const unsigned char* Pc = P + colbase;

    while (e0 + ST <= end0 && e1 + ST <= end1) {
        uint2 d0[U], d1[U];
        #pragma unroll
        for (int u = 0; u < U; ++u) {
            int s = csrc[e0 + g + u * G];
            d0[u] = *reinterpret_cast<const uint2*>(Pc + (size_t)s * F);
        }
        #pragma unroll
        for (int u = 0; u < U; ++u) {
            int s = csrc[e1 + g + u * G];
            d1[u] = *reinterpret_cast<const uint2*>(Pc + (size_t)s * F);
        }
        #pragma unroll
        for (int u = 0; u < U; ++u) { accf8(a0, d0[u]); accf8(a1, d1[u]); }
        e0 += ST; e1 += ST;
    }
    while (e0 + ST <= end0) {
        uint2 d[U];
        #pragma unroll
        for (int u = 0; u < U; ++u) {
            int s = csrc[e0 + g + u * G];
            d[u] = *reinterpret_cast<const uint2*>(Pc + (size_t)s * F);
        }
        #pragma unroll
        for (int u = 0; u < U; ++u) accf8(a0, d[u]);
        e0 += ST;
    }
    for (int e = e0 + g; e < end0; e += G) {
        int s = csrc[e];
        uint2 d = *reinterpret_cast<const uint2*>(Pc + (size_t)s * F);
        accf8(a0, d);
    }
    while (e1 + ST <= end1) {
        uint2 d[U];
        #pragma unroll
        for (int u = 0; u < U; ++u) {
            int s = csrc[e1 + g + u * G];
            d[u] = *reinterpret_cast<const uint2*>(Pc + (size_t)s * F);
        }
        #pragma unroll
        for (int u = 0; u < U; ++u) accf8(a1, d[u]);
        e1 += ST;
    }
    for (int e = e1 + g; e < end1; e += G) {
        int s = csrc[e];
        uint2 d = *reinterpret_cast<const uint2*>(Pc + (size_t)s * F);
        accf8(a1, d);
    }

    #pragma unroll
    for (int off = LPG; off < 64; off <<= 1) {
        #pragma unroll
        for (int i = 0; i < 8; ++i) {
            a0[i] += __shfl_xor(a0[i], off);
            a1[i] += __shfl_xor(a1[i], off);
        }
    }

    float inv0 = 1.f / fmaxf((float)(end0 - b0), 1.f);
    float inv1 = 1.f / fmaxf((float)(end1 - b1), 1.f);

    #pragma unroll
    for (int j = 0; j < 2; ++j) {
        if (j && !has1) break;
        int node = j ? n1 : n0;
        float* a = j ? a1 : a0;
        float inv = j ? inv1 : inv0;
        uint4 rr = *reinterpret_cast<const uint4*>(R + (size_t)node * F + colbase);
        float r[8];
        r[0] = bf2f(rr.x & 0xffff); r[1] = bf2f(rr.x >> 16);
        r[2] = bf2f(rr.y & 0xffff); r[3] = bf2f(rr.y >> 16);
        r[4] = bf2f(rr.z & 0xffff); r[5] = bf2f(rr.z >> 16);
        r[6] = bf2f(rr.w & 0xffff); r[7] = bf2f(rr.w >> 16);
        float4 bA = *reinterpret_cast<const float4*>(bias + colbase);
        float4 bB = *reinterpret_cast<const float4*>(bias + colbase + 4);
        float bv[8] = {bA.x, bA.y, bA.z, bA.w, bB.x, bB.y, bB.z, bB.w};
        float v[8];
        #pragma unroll
        for (int i = 0; i < 8; ++i) v[i] = a[i] * inv + r[i] + bv[i];

        if constexpr (!FINAL) {
            if (lane < LPG) {
                uint_t w[4];
                #pragma unroll
                for (int p = 0; p < 4; ++p) {
                    float v0 = fmaxf(v[2 * p], 0.f);
                    float v1 = fmaxf(v[2 * p + 1], 0.f);
                    w[p] = (uint_t)f2bf(v0) | ((uint_t)f2bf(v1) << 16);
                }
                *reinterpret_cast<uint4*>(H + (size_t)node * F + colbase) =
                    make_uint4(w[0], w[1], w[2], w[3]);
            }
        } else {
            float m = v[0];
            #pragma unroll
            for (int i = 1; i < 8; ++i) m = fmaxf(m, v[i]);
            #pragma unroll
            for (int off = 1; off < LPG; off <<= 1) m = fmaxf(m, __shfl_xor(m, off));
            float s = 0.f;
            #pragma unroll
            for (int i = 0; i < 8; ++i) s += expf(v[i] - m);
            #pragma unroll
            for (int off = 1; off < LPG; off <<= 1) s += __shfl_xor(s, off);
            float ls = m + logf(s);
            if (lane < LPG) {
                float* ho = hout + (size_t)node * 64 + colbase;
                float* lo = lout + (size_t)node * 64 + colbase;
                *reinterpret_cast<float4*>(ho) = make_float4(v[0], v[1], v[2], v[3]);
                *reinterpret_cast<float4*>(ho + 4) = make_float4(v[4], v[5], v[6], v[7]);
                *reinterpret_cast<float4*>(lo) =
                    make_float4(v[0] - ls, v[1] - ls, v[2] - ls, v[3] - ls);
                *reinterpret_cast<float4*>(lo + 4) =
                    make_float4(v[4] - ls, v[5] - ls, v[6] - ls, v[7] - ls);
            }
        }
    }
}

extern "C" void kernel_launch(void* const* d_in, const int* in_sizes, int n_in,
                              void* d_out, int out_size, void* d_ws, size_t ws_size,
                              hipStream_t stream) {
    const float* x   = (const float*)d_in[0];
    const int*   ei  = (const int*)d_in[1];
    const float* W1l = (const float*)d_in[2];
    const float* b1  = (const float*)d_in[3];
    const float* W1r = (const float*)d_in[4];
    const float* W2l = (const float*)d_in[5];
    const float* b2  = (const float*)d_in[6];
    const float* W2r = (const float*)d_in[7];
    const float* W3l = (const float*)d_in[8];
    const float* b3  = (const float*)d_in[9];
    const float* W3r = (const float*)d_in[10];
    const int* esrc = ei;
    const int* edst = ei + N_EDGES;

    char* ws = (char*)d_ws;
    size_t off = 0;
    auto alloc = [&](size_t b) { void* p = ws + off; off = (off + b + 255) & ~(size_t)255; return p; };
    unsigned char* P1 = (unsigned char*)alloc((size_t)MP * 256);  // fp8; reused as P2/P3
    ushort_t* R1 = (ushort_t*)alloc((size_t)MP * 256 * 2);        // bf16; reused as R2/R3
    ushort_t* H1 = (ushort_t*)alloc((size_t)MP * 256 * 2);
    ushort_t* H2 = (ushort_t*)alloc((size_t)MP * 128 * 2);
    int* offs = (int*)alloc((N_NODES + 1) * 4);
    int* dcnt = (int*)alloc(N_NODES * 4);
    int* bcur = (int*)alloc(NB * 4);
    ushort_t* csrc = (ushort_t*)alloc(N_EDGES * 2);
    uint_t* ebuf = (uint_t*)alloc((size_t)N_EDGES * 4);
    int* bsum = (int*)alloc(256 * 4);
    ushort_t* pB1 = (ushort_t*)alloc(256 * 512 * 2);
    ushort_t* pB2 = (ushort_t*)alloc(256 * 256 * 2);
    ushort_t* pB3 = (ushort_t*)alloc(128 * 128 * 2);

    unsigned char* P2 = P1;
    ushort_t* R2 = R1;
    unsigned char* P3 = P1;
    ushort_t* R3 = R1;

    int nScanBlocks = (N_NODES + 255) / 256;  // 196

    // pack weights + zero dcnt (one dispatch, no memset)
    pack_all_k<<<(26624 + 12500 + 255) / 256, 256, 0, stream>>>(
        W1l, W1r, W2l, W2r, W3l, W3r, pB1, pB2, pB3, dcnt);

    // CSR build (reused by all 3 layers)
    deg_k<<<(N_EDGES + 255) / 256, 256, 0, stream>>>(edst, dcnt, N_EDGES);
    scan1_k<<<nScanBlocks, 256, 0, stream>>>(dcnt, offs, bsum, N_NODES);
    scan2_k<<<1, 256, 0, stream>>>(bsum, nScanBlocks);
    scan3_k<<<nScanBlocks, 256, 0, stream>>>(offs, bsum, bcur, N_NODES, N_EDGES);
    binA_k<<<(N_EDGES + 2047) / 2048, 256, 0, stream>>>(esrc, edst, bcur, ebuf, N_EDGES);
    binB_k<<<NB, 256, 0, stream>>>(ebuf, offs, csrc);

    constexpr int BPG = 512;                   // blocks per col-group
    int aggGrid = ((N_NODES + 1) / 2 + 3) / 4; // 6250 blocks (2 nodes/wave, 4 waves)
    float* hout = (float*)d_out;
    float* lout = hout + (size_t)N_NODES * 64;

    // layer 1: P1(fp8)|R1(bf16) = x(f32) @ [W1l|W1r]; h1 = relu(mean(P1)+R1+b1)
    gemm_k<256, 512, 128, 256, true, BPG><<<4 * BPG, 256, 0, stream>>>(x, pB1, P1, R1, N_NODES);
    aggP8_k<256, false><<<aggGrid, 256, 0, stream>>>(
        P1, offs, csrc, R1, b1, H1, nullptr, nullptr, N_NODES);
    // layer 2
    gemm_k<256, 256, 128, 128, false, BPG><<<2 * BPG, 256, 0, stream>>>(H1, pB2, P2, R2, N_NODES);
    aggP8_k<128, false><<<aggGrid, 256, 0, stream>>>(
        P2, offs, csrc, R2, b2, H2, nullptr, nullptr, N_NODES);
    // layer 3: P3(fp8)|R3(bf16) = H2 @ [W3l|W3r]; fused mean+bias+log_softmax
    gemm_k<128, 128, 128, 64, false, BPG><<<BPG, 256, 0, stream>>>(H2, pB3, P3, R3, N_NODES);
    aggP8_k<64, true><<<aggGrid, 256, 0, stream>>>(
        P3, offs, csrc, R3, b3, nullptr, hout, lout, N_NODES);
}

// Round 14
// 261.803 us; speedup vs baseline: 1.0583x; 1.0583x over previous
//
#include <hip/hip_runtime.h>
#include <hip/hip_bf16.h>

#define N_NODES 50000
#define N_EDGES 800000
#define MP 50048  // N_NODES padded to multiple of 64
#define NB 98     // dst buckets of 512 nodes
#define BSH 9

typedef unsigned short ushort_t;
typedef unsigned int uint_t;
typedef __attribute__((ext_vector_type(8))) __bf16 bf16x8;
typedef __attribute__((ext_vector_type(4))) float f32x4;
typedef __attribute__((ext_vector_type(2))) float f32x2;

__device__ __forceinline__ float bf2f(uint_t u) {
    union { uint_t i; float f; } v; v.i = u << 16; return v.f;
}
__device__ __forceinline__ ushort_t f2bf(float f) {
    union { float f; uint_t i; } v; v.f = f;
    uint_t u = v.i;
    return (ushort_t)((u + 0x7FFFu + ((u >> 16) & 1u)) >> 16);
}
__device__ __forceinline__ void accf8(float* a, uint2 d) {
    f32x2 p;
    p = __builtin_amdgcn_cvt_pk_f32_fp8(d.x, false); a[0] += p.x; a[1] += p.y;
    p = __builtin_amdgcn_cvt_pk_f32_fp8(d.x, true);  a[2] += p.x; a[3] += p.y;
    p = __builtin_amdgcn_cvt_pk_f32_fp8(d.y, false); a[4] += p.x; a[5] += p.y;
    p = __builtin_amdgcn_cvt_pk_f32_fp8(d.y, true);  a[6] += p.x; a[7] += p.y;
}
__device__ __forceinline__ uint_t pk_hi(float a, float b) {
    return __builtin_amdgcn_perm(__float_as_uint(b), __float_as_uint(a), 0x07060302);
}

// ---------------- CSR build ----------------
__global__ void deg_k(const int* __restrict__ dst, int* __restrict__ deg, int E) {
    int e = blockIdx.x * 256 + threadIdx.x;
    if (e < E) atomicAdd(&deg[dst[e]], 1);
}

__global__ void scan1_k(const int* __restrict__ deg, int* __restrict__ offs,
                        int* __restrict__ bsum, int n) {
    __shared__ int s[256];
    int i = blockIdx.x * 256 + threadIdx.x;
    int v = (i < n) ? deg[i] : 0;
    s[threadIdx.x] = v;
    __syncthreads();
    #pragma unroll
    for (int d = 1; d < 256; d <<= 1) {
        int t = (threadIdx.x >= d) ? s[threadIdx.x - d] : 0;
        __syncthreads();
        s[threadIdx.x] += t;
        __syncthreads();
    }
    if (i < n) offs[i] = s[threadIdx.x] - v;   // exclusive
    if (threadIdx.x == 255) bsum[blockIdx.x] = s[255];
}

__global__ void scan2_k(int* __restrict__ bsum, int nb) {  // single block
    __shared__ int s[256];
    int v = (threadIdx.x < nb) ? bsum[threadIdx.x] : 0;
    s[threadIdx.x] = v;
    __syncthreads();
    #pragma unroll
    for (int d = 1; d < 256; d <<= 1) {
        int t = (threadIdx.x >= d) ? s[threadIdx.x - d] : 0;
        __syncthreads();
        s[threadIdx.x] += t;
        __syncthreads();
    }
    if (threadIdx.x < nb) bsum[threadIdx.x] = s[threadIdx.x] - v;  // exclusive
}

__global__ void scan3_k(int* __restrict__ offs, const int* __restrict__ bsum,
                        int* __restrict__ bcur, int n, int E) {
    int i = blockIdx.x * 256 + threadIdx.x;
    if (i < n) {
        int v = offs[i] + bsum[blockIdx.x];
        offs[i] = v;
        if ((i & 511) == 0) bcur[i >> BSH] = v;
    }
    if (i == 0) offs[n] = E;
}

// ---- Phase A: bin edges by dst>>9 into ebuf (u32 = dst<<16 | src) ----
__global__ __launch_bounds__(256) void binA_k(const int* __restrict__ src,
                                              const int* __restrict__ dst,
                                              int* __restrict__ bcur,
                                              uint_t* __restrict__ ebuf, int E) {
    __shared__ int cnt[NB];
    __shared__ int base[NB];
    int t = threadIdx.x;
    if (t < NB) cnt[t] = 0;
    __syncthreads();
    int myE = blockIdx.x * 2048 + t * 8;
    uint_t pk[8];
    int bk[8];
    int nval = 0;
    if (myE + 8 <= E) {
        int4 d0 = *reinterpret_cast<const int4*>(dst + myE);
        int4 d1 = *reinterpret_cast<const int4*>(dst + myE + 4);
        int4 s0 = *reinterpret_cast<const int4*>(src + myE);
        int4 s1 = *reinterpret_cast<const int4*>(src + myE + 4);
        int dd[8] = {d0.x, d0.y, d0.z, d0.w, d1.x, d1.y, d1.z, d1.w};
        int ss[8] = {s0.x, s0.y, s0.z, s0.w, s1.x, s1.y, s1.z, s1.w};
        nval = 8;
        #pragma unroll
        for (int i = 0; i < 8; ++i) {
            pk[i] = ((uint_t)dd[i] << 16) | (uint_t)ss[i];
            bk[i] = dd[i] >> BSH;
            atomicAdd(&cnt[bk[i]], 1);
        }
    } else {
        for (int e = myE; e < E && nval < 8; ++e) {
            int d = dst[e];
            pk[nval] = ((uint_t)d << 16) | (uint_t)src[e];
            bk[nval] = d >> BSH;
            atomicAdd(&cnt[bk[nval]], 1);
            ++nval;
        }
    }
    __syncthreads();
    if (t < NB) {
        int c = cnt[t];
        base[t] = c ? atomicAdd(&bcur[t], c) : 0;
        cnt[t] = 0;
    }
    __syncthreads();
    for (int i = 0; i < nval; ++i) {
        int r = atomicAdd(&cnt[bk[i]], 1);
        ebuf[base[bk[i]] + r] = pk[i];
    }
}

// ---- Phase B: per bucket, LDS-sort to per-node order, coalesced csrc write ----
__global__ __launch_bounds__(256) void binB_k(const uint_t* __restrict__ ebuf,
                                              const int* __restrict__ offs,
                                              ushort_t* __restrict__ csrc) {
    __shared__ int lcur[512];
    __shared__ ushort_t lsrc[10240];
    int b = blockIdx.x;
    int n0 = b << BSH;
    int n1 = min(n0 + 512, N_NODES);
    int t = threadIdx.x;
    int obase = offs[n0];
    int cntE = offs[n1] - obase;
    for (int i = t; i < n1 - n0; i += 256) lcur[i] = offs[n0 + i] - obase;
    __syncthreads();
    for (int i = t; i < cntE; i += 256) {
        uint_t pk = ebuf[obase + i];
        int d = (int)(pk >> 16) - n0;
        int p = atomicAdd(&lcur[d], 1);
        lsrc[p] = (ushort_t)(pk & 0xffffu);
    }
    __syncthreads();
    for (int i = t; i < cntE; i += 256) csrc[obase + i] = lsrc[i];
}

// ---------------- fused weight packing + dcnt zeroing ----------------
__device__ __forceinline__ void pack_one(const float* Wl, const float* Wr,
                                         ushort_t* P, int K, int F, int t) {
    int NOUT = 2 * F;
    int lane = t & 63;
    int frag = t >> 6;
    int nct = NOUT / 16;
    int ct = frag % nct;
    int kt = frag / nct;
    int col = ct * 16 + (lane & 15);
    const float* W = (col < F) ? Wl : Wr;
    int c = (col < F) ? col : col - F;
    int k0 = kt * 32 + (lane >> 4) * 8;
    uint_t w[4];
    #pragma unroll
    for (int p = 0; p < 4; ++p) {
        ushort_t lo = f2bf(W[(size_t)(k0 + 2 * p) * F + c]);
        ushort_t hi = f2bf(W[(size_t)(k0 + 2 * p + 1) * F + c]);
        w[p] = (uint_t)lo | ((uint_t)hi << 16);
    }
    *(reinterpret_cast<uint4*>(P) + t) = make_uint4(w[0], w[1], w[2], w[3]);
}

__global__ void pack_all_k(const float* __restrict__ W1l, const float* __restrict__ W1r,
                           const float* __restrict__ W2l, const float* __restrict__ W2r,
                           const float* __restrict__ W3l, const float* __restrict__ W3r,
                           ushort_t* __restrict__ pB1, ushort_t* __restrict__ pB2,
                           ushort_t* __restrict__ pB3, int* __restrict__ dcnt) {
    int tid = blockIdx.x * 256 + threadIdx.x;
    if (tid < 16384)       pack_one(W1l, W1r, pB1, 256, 256, tid);
    else if (tid < 24576)  pack_one(W2l, W2r, pB2, 256, 128, tid - 16384);
    else if (tid < 26624)  pack_one(W3l, W3r, pB3, 128, 64, tid - 24576);
    else {
        int z = tid - 26624;
        if (z < 12500)
            *(reinterpret_cast<uint4*>(dcnt) + z) = make_uint4(0, 0, 0, 0);
    }
}

// ---------------- layer-1 GEMM (r12 config): [P1|R1] = x @ pB1 ----------------
template <int K, int NOUT, int NCB, int PF, bool F32A, int BPG>
__global__ __launch_bounds__(256, 2) void gemm_k(
    const void* __restrict__ Av, const ushort_t* __restrict__ Bp,
    unsigned char* __restrict__ Pout, ushort_t* __restrict__ Rout, int nvalid) {
    constexpr int KT = K / 32;
    constexpr int CTW = NCB / 64;
    constexpr int NCG = NOUT / NCB;
    constexpr int RS = NOUT - PF;
    constexpr int PADE = K + 8;
    constexpr int NTILES = MP / 32;
    constexpr int NWR = K / 64;
    __shared__ ushort_t Atile[32 * PADE];

    int cg = (NCG > 1) ? ((int)blockIdx.x % NCG) : 0;
    int bid = (NCG > 1) ? ((int)blockIdx.x / NCG) : (int)blockIdx.x;
    int wave = threadIdx.x >> 6;
    int lane = threadIdx.x & 63;
    int ct0 = cg * (NCB / 16) + wave * CTW;

    bf16x8 breg[KT][CTW];
    #pragma unroll
    for (int kt = 0; kt < KT; ++kt)
        #pragma unroll
        for (int ct = 0; ct < CTW; ++ct)
            breg[kt][ct] = *reinterpret_cast<const bf16x8*>(
                Bp + ((size_t)(kt * (NOUT / 16) + ct0 + ct) * 64 + lane) * 8);

    int arowoff = lane & 15;
    int r0 = (lane >> 4) * 4;
    int srow = threadIdx.x >> 3;
    int sel = (threadIdx.x & 7) * (K / 8);

    float4 fr[2 * NWR];
    uint4 ur[NWR];

    auto loadregs = [&](int t) {
        int grow = min(t * 32 + srow, nvalid - 1);
        if (F32A) {
            const float* A = (const float*)Av + (size_t)grow * K + sel;
            #pragma unroll
            for (int i = 0; i < NWR; ++i) {
                fr[2 * i]     = *reinterpret_cast<const float4*>(A + i * 8);
                fr[2 * i + 1] = *reinterpret_cast<const float4*>(A + i * 8 + 4);
            }
        } else {
            const ushort_t* A = (const ushort_t*)Av + (size_t)grow * K + sel;
            #pragma unroll
            for (int i = 0; i < NWR; ++i)
                ur[i] = *reinterpret_cast<const uint4*>(A + i * 8);
        }
    };
    auto writelds = [&]() {
        ushort_t* dst = &Atile[srow * PADE + sel];
        if (F32A) {
            #pragma unroll
            for (int i = 0; i < NWR; ++i) {
                uint4 w;
                w.x = pk_hi(fr[2 * i].x, fr[2 * i].y);
                w.y = pk_hi(fr[2 * i].z, fr[2 * i].w);
                w.z = pk_hi(fr[2 * i + 1].x, fr[2 * i + 1].y);
                w.w = pk_hi(fr[2 * i + 1].z, fr[2 * i + 1].w);
                *reinterpret_cast<uint4*>(dst + i * 8) = w;
            }
        } else {
            #pragma unroll
            for (int i = 0; i < NWR; ++i)
                *reinterpret_cast<uint4*>(dst + i * 8) = ur[i];
        }
    };

    loadregs(bid);
    writelds();

    for (int t = bid; t < NTILES; t += BPG) {
        __syncthreads();
        int tn = t + BPG;
        if (tn < NTILES) loadregs(tn);

        f32x4 acc[2][CTW];
        #pragma unroll
        for (int r = 0; r < 2; ++r)
            #pragma unroll
            for (int c = 0; c < CTW; ++c) acc[r][c] = (f32x4){0.f, 0.f, 0.f, 0.f};

        const ushort_t* A0 = &Atile[arowoff * PADE + (lane >> 4) * 8];
        #pragma unroll
        for (int kt = 0; kt < KT; ++kt) {
            bf16x8 x0 = *reinterpret_cast<const bf16x8*>(A0 + kt * 32);
            bf16x8 x1 = *reinterpret_cast<const bf16x8*>(A0 + 16 * PADE + kt * 32);
            #pragma unroll
            for (int ct = 0; ct < CTW; ++ct) {
                acc[0][ct] = __builtin_amdgcn_mfma_f32_16x16x32_bf16(breg[kt][ct], x0, acc[0][ct], 0, 0, 0);
                acc[1][ct] = __builtin_amdgcn_mfma_f32_16x16x32_bf16(breg[kt][ct], x1, acc[1][ct], 0, 0, 0);
            }
        }

        int rowBase = t * 32;
        #pragma unroll
        for (int r = 0; r < 2; ++r) {
            int xrow = rowBase + r * 16 + arowoff;
            #pragma unroll
            for (int ct = 0; ct < CTW; ++ct) {
                int wc = (ct0 + ct) * 16 + r0;
                f32x4 v = acc[r][ct];
                if (PF > 0 && wc < PF) {
                    uint_t u = __builtin_amdgcn_cvt_pk_fp8_f32(v[0], v[1], 0u, false);
                    u = __builtin_amdgcn_cvt_pk_fp8_f32(v[2], v[3], u, true);
                    *reinterpret_cast<uint_t*>(Pout + (size_t)xrow * PF + wc) = u;
                } else {
                    uint2 w;
                    w.x = (uint_t)f2bf(v[0]) | ((uint_t)f2bf(v[1]) << 16);
                    w.y = (uint_t)f2bf(v[2]) | ((uint_t)f2bf(v[3]) << 16);
                    *reinterpret_cast<uint2*>(Rout + (size_t)xrow * RS + (wc - PF)) = w;
                }
            }
        }

        __syncthreads();
        if (tn < NTILES) writelds();
    }
}

// ---------------- FUSED: agg layer l (fp8 P + bf16 R -> h in LDS) + GEMM layer l+1 ----------------
// Block owns 64 nodes (= 64 output rows): agg phase computes h rows into LDS
// (relu(mean(Pin)+Rin+bias)); then the 64xFIN tile is multiplied by packed
// B (next layer) -> Pout(fp8)|Rout(bf16). No global H round-trip, no extra sync.
template <int FIN, int NOUT, int PF>
__global__ __launch_bounds__(256, 2) void fusedAG_k(
    const unsigned char* __restrict__ Pin, const int* __restrict__ offs,
    const ushort_t* __restrict__ csrc, const ushort_t* __restrict__ Rin,
    const float* __restrict__ bias, const ushort_t* __restrict__ Bp,
    unsigned char* __restrict__ Pout, ushort_t* __restrict__ Rout, int n) {
    constexpr int LPG = FIN / 8;           // lanes covering one row (8B fp8 each)
    constexpr int G = 64 / LPG;            // edge groups
    constexpr int U = (G >= 4) ? 1 : (4 / G);
    constexpr int ST = G * U;
    constexpr int PADE = FIN + 8;
    constexpr int KT = FIN / 32;
    constexpr int CTW = NOUT / 64;
    constexpr int RS = NOUT - PF;
    __shared__ ushort_t Htile[64 * PADE];

    int wave = threadIdx.x >> 6;
    int lane = threadIdx.x & 63;
    int blockBase = blockIdx.x * 64;
    int g = lane / LPG;
    int sub = lane & (LPG - 1);
    int colbase = sub * 8;
    const unsigned char* Pc = Pin + colbase;

    // ---- agg phase: 16 nodes per wave (8 pairs) ----
    for (int i = 0; i < 8; ++i) {
        int row0 = wave * 16 + 2 * i;
        int n0 = blockBase + row0, n1 = n0 + 1;
        bool has0 = (n0 < n), has1 = (n1 < n);
        int b0 = 0, end0 = 0, b1 = 0, end1 = 0;
        if (has0) { b0 = offs[n0]; end0 = offs[n0 + 1]; }
        if (has1) { b1 = offs[n1]; end1 = offs[n1 + 1]; }

        float a0[8] = {0,0,0,0,0,0,0,0};
        float a1[8] = {0,0,0,0,0,0,0,0};
        int e0 = b0, e1 = b1;

        while (e0 + ST <= end0 && e1 + ST <= end1) {
            uint2 d0[U], d1[U];
            #pragma unroll
            for (int u = 0; u < U; ++u) {
                int s = csrc[e0 + g + u * G];
                d0[u] = *reinterpret_cast<const uint2*>(Pc + (size_t)s * FIN);
            }
            #pragma unroll
            for (int u = 0; u < U; ++u) {
                int s = csrc[e1 + g + u * G];
                d1[u] = *reinterpret_cast<const uint2*>(Pc + (size_t)s * FIN);
            }
            #pragma unroll
            for (int u = 0; u < U; ++u) { accf8(a0, d0[u]); accf8(a1, d1[u]); }
            e0 += ST; e1 += ST;
        }
        while (e0 + ST <= end0) {
            uint2 d[U];
            #pragma unroll
            for (int u = 0; u < U; ++u) {
                int s = csrc[e0 + g + u * G];
                d[u] = *reinterpret_cast<const uint2*>(Pc + (size_t)s * FIN);
            }
            #pragma unroll
            for (int u = 0; u < U; ++u) accf8(a0, d[u]);
            e0 += ST;
        }
        for (int e = e0 + g; e < end0; e += G) {
            int s = csrc[e];
            uint2 d = *reinterpret_cast<const uint2*>(Pc + (size_t)s * FIN);
            accf8(a0, d);
        }
        while (e1 + ST <= end1) {
            uint2 d[U];
            #pragma unroll
            for (int u = 0; u < U; ++u) {
                int s = csrc[e1 + g + u * G];
                d[u] = *reinterpret_cast<const uint2*>(Pc + (size_t)s * FIN);
            }
            #pragma unroll
            for (int u = 0; u < U; ++u) accf8(a1, d[u]);
            e1 += ST;
        }
        for (int e = e1 + g; e < end1; e += G) {
            int s = csrc[e];
            uint2 d = *reinterpret_cast<const uint2*>(Pc + (size_t)s * FIN);
            accf8(a1, d);
        }

        #pragma unroll
        for (int off = LPG; off < 64; off <<= 1) {
            #pragma unroll
            for (int k = 0; k < 8; ++k) {
                a0[k] += __shfl_xor(a0[k], off);
                a1[k] += __shfl_xor(a1[k], off);
            }
        }

        if (lane < LPG) {
            float inv0 = 1.f / fmaxf((float)(end0 - b0), 1.f);
            float inv1 = 1.f / fmaxf((float)(end1 - b1), 1.f);
            float4 bA = *reinterpret_cast<const float4*>(bias + colbase);
            float4 bB = *reinterpret_cast<const float4*>(bias + colbase + 4);
            float bv[8] = {bA.x, bA.y, bA.z, bA.w, bB.x, bB.y, bB.z, bB.w};
            #pragma unroll
            for (int j = 0; j < 2; ++j) {
                int node = j ? n1 : n0;
                int row = row0 + j;
                uint4 out = make_uint4(0, 0, 0, 0);
                if ((j ? has1 : has0)) {
                    float* a = j ? a1 : a0;
                    float inv = j ? inv1 : inv0;
                    uint4 rr = *reinterpret_cast<const uint4*>(Rin + (size_t)node * FIN + colbase);
                    float r[8];
                    r[0] = bf2f(rr.x & 0xffff); r[1] = bf2f(rr.x >> 16);
                    r[2] = bf2f(rr.y & 0xffff); r[3] = bf2f(rr.y >> 16);
                    r[4] = bf2f(rr.z & 0xffff); r[5] = bf2f(rr.z >> 16);
                    r[6] = bf2f(rr.w & 0xffff); r[7] = bf2f(rr.w >> 16);
                    uint_t w[4];
                    #pragma unroll
                    for (int p = 0; p < 4; ++p) {
                        float v0 = fmaxf(a[2 * p] * inv + r[2 * p] + bv[2 * p], 0.f);
                        float v1 = fmaxf(a[2 * p + 1] * inv + r[2 * p + 1] + bv[2 * p + 1], 0.f);
                        w[p] = (uint_t)f2bf(v0) | ((uint_t)f2bf(v1) << 16);
                    }
                    out = make_uint4(w[0], w[1], w[2], w[3]);
                }
                *reinterpret_cast<uint4*>(&Htile[(size_t)row * PADE + colbase]) = out;
            }
        }
    }
    __syncthreads();

    // ---- gemm phase: Htile[64][FIN] @ Bp -> Pout|Rout (rows blockBase..+63) ----
    int arowoff = lane & 15;
    int r0 = (lane >> 4) * 4;
    int ct0 = wave * CTW;

    f32x4 acc[4][CTW];
    #pragma unroll
    for (int r = 0; r < 4; ++r)
        #pragma unroll
        for (int c = 0; c < CTW; ++c) acc[r][c] = (f32x4){0.f, 0.f, 0.f, 0.f};

    const ushort_t* A0 = &Htile[arowoff * PADE + (lane >> 4) * 8];
    bf16x8 bcur[CTW], bnxt[CTW];
    #pragma unroll
    for (int ct = 0; ct < CTW; ++ct)
        bcur[ct] = *reinterpret_cast<const bf16x8*>(
            Bp + ((size_t)(ct0 + ct) * 64 + lane) * 8);

    #pragma unroll
    for (int kt = 0; kt < KT; ++kt) {
        if (kt + 1 < KT) {
            #pragma unroll
            for (int ct = 0; ct < CTW; ++ct)
                bnxt[ct] = *reinterpret_cast<const bf16x8*>(
                    Bp + ((size_t)((kt + 1) * (NOUT / 16) + ct0 + ct) * 64 + lane) * 8);
        }
        bf16x8 x0 = *reinterpret_cast<const bf16x8*>(A0 + kt * 32);
        bf16x8 x1 = *reinterpret_cast<const bf16x8*>(A0 + 16 * PADE + kt * 32);
        bf16x8 x2 = *reinterpret_cast<const bf16x8*>(A0 + 32 * PADE + kt * 32);
        bf16x8 x3 = *reinterpret_cast<const bf16x8*>(A0 + 48 * PADE + kt * 32);
        #pragma unroll
        for (int ct = 0; ct < CTW; ++ct) {
            acc[0][ct] = __builtin_amdgcn_mfma_f32_16x16x32_bf16(bcur[ct], x0, acc[0][ct], 0, 0, 0);
            acc[1][ct] = __builtin_amdgcn_mfma_f32_16x16x32_bf16(bcur[ct], x1, acc[1][ct], 0, 0, 0);
            acc[2][ct] = __builtin_amdgcn_mfma_f32_16x16x32_bf16(bcur[ct], x2, acc[2][ct], 0, 0, 0);
            acc[3][ct] = __builtin_amdgcn_mfma_f32_16x16x32_bf16(bcur[ct], x3, acc[3][ct], 0, 0, 0);
        }
        #pragma unroll
        for (int ct = 0; ct < CTW; ++ct) bcur[ct] = bnxt[ct];
    }

    #pragma unroll
    for (int r = 0; r < 4; ++r) {
        int xrow = blockBase + r * 16 + arowoff;
        #pragma unroll
        for (int ct = 0; ct < CTW; ++ct) {
            int wc = (ct0 + ct) * 16 + r0;
            f32x4 v = acc[r][ct];
            if (wc < PF) {
                uint_t u = __builtin_amdgcn_cvt_pk_fp8_f32(v[0], v[1], 0u, false);
                u = __builtin_amdgcn_cvt_pk_fp8_f32(v[2], v[3], u, true);
                *reinterpret_cast<uint_t*>(Pout + (size_t)xrow * PF + wc) = u;
            } else {
                uint2 w;
                w.x = (uint_t)f2bf(v[0]) | ((uint_t)f2bf(v[1]) << 16);
                w.y = (uint_t)f2bf(v[2]) | ((uint_t)f2bf(v[3]) << 16);
                *reinterpret_cast<uint2*>(Rout + (size_t)xrow * RS + (wc - PF)) = w;
            }
        }
    }
}

// ---------------- final: aggregate (fp8 P3 + bf16 R3, F=64) + log_softmax ----------------
__global__ __launch_bounds__(256) void aggF_k(
    const unsigned char* __restrict__ P, const int* __restrict__ offs,
    const ushort_t* __restrict__ csrc, const ushort_t* __restrict__ R,
    const float* __restrict__ bias, float* __restrict__ hout,
    float* __restrict__ lout, int n) {
    constexpr int F = 64;
    constexpr int LPG = 8;
    constexpr int G = 8;
    int wid = (blockIdx.x * 256 + threadIdx.x) >> 6;
    int lane = threadIdx.x & 63;
    int g = lane / LPG;
    int sub = lane & (LPG - 1);
    int colbase = sub * 8;
    int n0 = 2 * wid, n1 = 2 * wid + 1;
    if (n0 >= n) return;
    bool has1 = (n1 < n);
    int b0 = offs[n0], end0 = offs[n0 + 1];
    int b1 = has1 ? offs[n1] : 0, end1 = has1 ? offs[n1 + 1] : 0;

    float a0[8] = {0,0,0,0,0,0,0,0};
    float a1[8] = {0,0,0,0,0,0,0,0};
    int e0 = b0, e1 = b1;
    const unsigned char* Pc = P + colbase;

    while (e0 + G <= end0 && e1 + G <= end1) {
        int s0 = csrc[e0 + g], s1 = csrc[e1 + g];
        uint2 d0 = *reinterpret_cast<const uint2*>(Pc + (size_t)s0 * F);
        uint2 d1 = *reinterpret_cast<const uint2*>(Pc + (size_t)s1 * F);
        accf8(a0, d0); accf8(a1, d1);
        e0 += G; e1 += G;
    }
    while (e0 + G <= end0) {
        int s = csrc[e0 + g];
        uint2 d = *reinterpret_cast<const uint2*>(Pc + (size_t)s * F);
        accf8(a0, d);
        e0 += G;
    }
    for (int e = e0 + g; e < end0; e += G) {
        int s = csrc[e];
        uint2 d = *reinterpret_cast<const uint2*>(Pc + (size_t)s * F);
        accf8(a0, d);
    }
    while (e1 + G <= end1) {
        int s = csrc[e1 + g];
        uint2 d = *reinterpret_cast<const uint2*>(Pc + (size_t)s * F);
        accf8(a1, d);
        e1 += G;
    }
    for (int e = e1 + g; e < end1; e += G) {
        int s = csrc[e];
        uint2 d = *reinterpret_cast<const uint2*>(Pc + (size_t)s * F);
        accf8(a1, d);
    }

    #pragma unroll
    for (int off = LPG; off < 64; off <<= 1) {
        #pragma unroll
        for (int k = 0; k < 8; ++k) {
            a0[k] += __shfl_xor(a0[k], off);
            a1[k] += __shfl_xor(a1[k], off);
        }
    }

    float inv0 = 1.f / fmaxf((float)(end0 - b0), 1.f);
    float inv1 = 1.f / fmaxf((float)(end1 - b1), 1.f);

    #pragma unroll
    for (int j = 0; j < 2; ++j) {
        if (j && !has1) break;
        int node = j ? n1 : n0;
        float* a = j ? a1 : a0;
        float inv = j ? inv1 : inv0;
        uint4 rr = *reinterpret_cast<const uint4*>(R + (size_t)node * F + colbase);
        float r[8];
        r[0] = bf2f(rr.x & 0xffff); r[1] = bf2f(rr.x >> 16);
        r[2] = bf2f(rr.y & 0xffff); r[3] = bf2f(rr.y >> 16);
        r[4] = bf2f(rr.z & 0xffff); r[5] = bf2f(rr.z >> 16);
        r[6] = bf2f(rr.w & 0xffff); r[7] = bf2f(rr.w >> 16);
        float4 bA = *reinterpret_cast<const float4*>(bias + colbase);
        float4 bB = *reinterpret_cast<const float4*>(bias + colbase + 4);
        float bv[8] = {bA.x, bA.y, bA.z, bA.w, bB.x, bB.y, bB.z, bB.w};
        float v[8];
        #pragma unroll
        for (int k = 0; k < 8; ++k) v[k] = a[k] * inv + r[k] + bv[k];

        float m = v[0];
        #pragma unroll
        for (int k = 1; k < 8; ++k) m = fmaxf(m, v[k]);
        #pragma unroll
        for (int off = 1; off < LPG; off <<= 1) m = fmaxf(m, __shfl_xor(m, off));
        float s = 0.f;
        #pragma unroll
        for (int k = 0; k < 8; ++k) s += expf(v[k] - m);
        #pragma unroll
        for (int off = 1; off < LPG; off <<= 1) s += __shfl_xor(s, off);
        float ls = m + logf(s);
        if (lane < LPG) {
            float* ho = hout + (size_t)node * 64 + colbase;
            float* lo = lout + (size_t)node * 64 + colbase;
            *reinterpret_cast<float4*>(ho) = make_float4(v[0], v[1], v[2], v[3]);
            *reinterpret_cast<float4*>(ho + 4) = make_float4(v[4], v[5], v[6], v[7]);
            *reinterpret_cast<float4*>(lo) =
                make_float4(v[0] - ls, v[1] - ls, v[2] - ls, v[3] - ls);
            *reinterpret_cast<float4*>(lo + 4) =
                make_float4(v[4] - ls, v[5] - ls, v[6] - ls, v[7] - ls);
        }
    }
}

extern "C" void kernel_launch(void* const* d_in, const int* in_sizes, int n_in,
                              void* d_out, int out_size, void* d_ws, size_t ws_size,
                              hipStream_t stream) {
    const float* x   = (const float*)d_in[0];
    const int*   ei  = (const int*)d_in[1];
    const float* W1l = (const float*)d_in[2];
    const float* b1  = (const float*)d_in[3];
    const float* W1r = (const float*)d_in[4];
    const float* W2l = (const float*)d_in[5];
    const float* b2  = (const float*)d_in[6];
    const float* W2r = (const float*)d_in[7];
    const float* W3l = (const float*)d_in[8];
    const float* b3  = (const float*)d_in[9];
    const float* W3r = (const float*)d_in[10];
    const int* esrc = ei;
    const int* edst = ei + N_EDGES;

    char* ws = (char*)d_ws;
    size_t off = 0;
    auto alloc = [&](size_t b) { void* p = ws + off; off = (off + b + 255) & ~(size_t)255; return p; };
    unsigned char* P1 = (unsigned char*)alloc((size_t)MP * 256);  // fp8
    ushort_t* R1 = (ushort_t*)alloc((size_t)MP * 256 * 2);        // bf16
    unsigned char* P2 = (unsigned char*)alloc((size_t)MP * 128);  // fp8
    ushort_t* R2 = (ushort_t*)alloc((size_t)MP * 128 * 2);        // bf16
    unsigned char* P3 = (unsigned char*)alloc((size_t)MP * 64);   // fp8
    ushort_t* R3 = (ushort_t*)alloc((size_t)MP * 64 * 2);         // bf16
    int* offs = (int*)alloc((N_NODES + 1) * 4);
    int* dcnt = (int*)alloc(N_NODES * 4);
    int* bcur = (int*)alloc(NB * 4);
    ushort_t* csrc = (ushort_t*)alloc(N_EDGES * 2);
    uint_t* ebuf = (uint_t*)alloc((size_t)N_EDGES * 4);
    int* bsum = (int*)alloc(256 * 4);
    ushort_t* pB1 = (ushort_t*)alloc(256 * 512 * 2);
    ushort_t* pB2 = (ushort_t*)alloc(256 * 256 * 2);
    ushort_t* pB3 = (ushort_t*)alloc(128 * 128 * 2);

    int nScanBlocks = (N_NODES + 255) / 256;  // 196

    // pack weights + zero dcnt
    pack_all_k<<<(26624 + 12500 + 255) / 256, 256, 0, stream>>>(
        W1l, W1r, W2l, W2r, W3l, W3r, pB1, pB2, pB3, dcnt);

    // CSR build
    deg_k<<<(N_EDGES + 255) / 256, 256, 0, stream>>>(edst, dcnt, N_EDGES);
    scan1_k<<<nScanBlocks, 256, 0, stream>>>(dcnt, offs, bsum, N_NODES);
    scan2_k<<<1, 256, 0, stream>>>(bsum, nScanBlocks);
    scan3_k<<<nScanBlocks, 256, 0, stream>>>(offs, bsum, bcur, N_NODES, N_EDGES);
    binA_k<<<(N_EDGES + 2047) / 2048, 256, 0, stream>>>(esrc, edst, bcur, ebuf, N_EDGES);
    binB_k<<<NB, 256, 0, stream>>>(ebuf, offs, csrc);

    constexpr int BPG = 512;
    int fusedGrid = MP / 64;                   // 782
    int aggGrid = ((N_NODES + 1) / 2 + 3) / 4; // 6250
    float* hout = (float*)d_out;
    float* lout = hout + (size_t)N_NODES * 64;

    // layer 1 GEMM: P1|R1 = x @ [W1l|W1r]
    gemm_k<256, 512, 256, 256, true, BPG><<<2 * BPG, 256, 0, stream>>>(x, pB1, P1, R1, N_NODES);
    // fused: agg1 (h1 in LDS) + GEMM2 -> P2|R2
    fusedAG_k<256, 256, 128><<<fusedGrid, 256, 0, stream>>>(
        P1, offs, csrc, R1, b1, pB2, P2, R2, N_NODES);
    // fused: agg2 (h2 in LDS) + GEMM3 -> P3|R3
    fusedAG_k<128, 128, 64><<<fusedGrid, 256, 0, stream>>>(
        P2, offs, csrc, R2, b2, pB3, P3, R3, N_NODES);
    // final: agg3 + bias + log_softmax
    aggF_k<<<aggGrid, 256, 0, stream>>>(P3, offs, csrc, R3, b3, hout, lout, N_NODES);
}

// Round 15
// 191.319 us; speedup vs baseline: 1.4482x; 1.3684x over previous
//
#include <hip/hip_runtime.h>
#include <hip/hip_bf16.h>

#define N_NODES 50000
#define N_EDGES 800000
#define MP 50048  // N_NODES padded to multiple of 64
#define NB 98     // dst buckets of 512 nodes
#define BSH 9
#define CAP 10240 // bucket capacity (mean 8192, +22 sigma)

typedef unsigned short ushort_t;
typedef unsigned int uint_t;
typedef __attribute__((ext_vector_type(8))) __bf16 bf16x8;
typedef __attribute__((ext_vector_type(4))) float f32x4;
typedef __attribute__((ext_vector_type(2))) float f32x2;

__device__ __forceinline__ float bf2f(uint_t u) {
    union { uint_t i; float f; } v; v.i = u << 16; return v.f;
}
__device__ __forceinline__ ushort_t f2bf(float f) {
    union { float f; uint_t i; } v; v.f = f;
    uint_t u = v.i;
    return (ushort_t)((u + 0x7FFFu + ((u >> 16) & 1u)) >> 16);
}
__device__ __forceinline__ void accf8(float* a, uint2 d) {
    f32x2 p;
    p = __builtin_amdgcn_cvt_pk_f32_fp8(d.x, false); a[0] += p.x; a[1] += p.y;
    p = __builtin_amdgcn_cvt_pk_f32_fp8(d.x, true);  a[2] += p.x; a[3] += p.y;
    p = __builtin_amdgcn_cvt_pk_f32_fp8(d.y, false); a[4] += p.x; a[5] += p.y;
    p = __builtin_amdgcn_cvt_pk_f32_fp8(d.y, true);  a[6] += p.x; a[7] += p.y;
}
__device__ __forceinline__ uint_t pk_hi(float a, float b) {
    return __builtin_amdgcn_perm(__float_as_uint(b), __float_as_uint(a), 0x07060302);
}

// ---------------- fused weight packing + bucket-cursor init ----------------
__device__ __forceinline__ void pack_one(const float* Wl, const float* Wr,
                                         ushort_t* P, int K, int F, int t) {
    int NOUT = 2 * F;
    int lane = t & 63;
    int frag = t >> 6;
    int nct = NOUT / 16;
    int ct = frag % nct;
    int kt = frag / nct;
    int col = ct * 16 + (lane & 15);
    const float* W = (col < F) ? Wl : Wr;
    int c = (col < F) ? col : col - F;
    int k0 = kt * 32 + (lane >> 4) * 8;
    uint_t w[4];
    #pragma unroll
    for (int p = 0; p < 4; ++p) {
        ushort_t lo = f2bf(W[(size_t)(k0 + 2 * p) * F + c]);
        ushort_t hi = f2bf(W[(size_t)(k0 + 2 * p + 1) * F + c]);
        w[p] = (uint_t)lo | ((uint_t)hi << 16);
    }
    *(reinterpret_cast<uint4*>(P) + t) = make_uint4(w[0], w[1], w[2], w[3]);
}

__global__ void pack_all_k(const float* __restrict__ W1l, const float* __restrict__ W1r,
                           const float* __restrict__ W2l, const float* __restrict__ W2r,
                           const float* __restrict__ W3l, const float* __restrict__ W3r,
                           ushort_t* __restrict__ pB1, ushort_t* __restrict__ pB2,
                           ushort_t* __restrict__ pB3, int* __restrict__ bcur) {
    int tid = blockIdx.x * 256 + threadIdx.x;
    if (tid < 16384)       pack_one(W1l, W1r, pB1, 256, 256, tid);
    else if (tid < 24576)  pack_one(W2l, W2r, pB2, 256, 128, tid - 16384);
    else if (tid < 26624)  pack_one(W3l, W3r, pB3, 128, 64, tid - 24576);
    else {
        int z = tid - 26624;
        if (z < NB) bcur[z] = z * CAP;   // bucket append cursors
    }
}

// ---- binA: append edges (u32 = dst<<16 | src) into fixed-capacity bucket regions ----
__global__ __launch_bounds__(256) void binA_k(const int* __restrict__ src,
                                              const int* __restrict__ dst,
                                              int* __restrict__ bcur,
                                              uint_t* __restrict__ ebuf, int E) {
    __shared__ int cnt[NB];
    __shared__ int base[NB];
    int t = threadIdx.x;
    if (t < NB) cnt[t] = 0;
    __syncthreads();
    int myE = blockIdx.x * 2048 + t * 8;
    uint_t pk[8];
    int bk[8];
    int nval = 0;
    if (myE + 8 <= E) {
        int4 d0 = *reinterpret_cast<const int4*>(dst + myE);
        int4 d1 = *reinterpret_cast<const int4*>(dst + myE + 4);
        int4 s0 = *reinterpret_cast<const int4*>(src + myE);
        int4 s1 = *reinterpret_cast<const int4*>(src + myE + 4);
        int dd[8] = {d0.x, d0.y, d0.z, d0.w, d1.x, d1.y, d1.z, d1.w};
        int ss[8] = {s0.x, s0.y, s0.z, s0.w, s1.x, s1.y, s1.z, s1.w};
        nval = 8;
        #pragma unroll
        for (int i = 0; i < 8; ++i) {
            pk[i] = ((uint_t)dd[i] << 16) | (uint_t)ss[i];
            bk[i] = dd[i] >> BSH;
            atomicAdd(&cnt[bk[i]], 1);
        }
    } else {
        for (int e = myE; e < E && nval < 8; ++e) {
            int d = dst[e];
            pk[nval] = ((uint_t)d << 16) | (uint_t)src[e];
            bk[nval] = d >> BSH;
            atomicAdd(&cnt[bk[nval]], 1);
            ++nval;
        }
    }
    __syncthreads();
    if (t < NB) {
        int c = cnt[t];
        base[t] = c ? atomicAdd(&bcur[t], c) : 0;
        cnt[t] = 0;
    }
    __syncthreads();
    for (int i = 0; i < nval; ++i) {
        int r = atomicAdd(&cnt[bk[i]], 1);
        ebuf[base[bk[i]] + r] = pk[i];
    }
}

// ---- scanB: exclusive scan of the 98 bucket counts (single small block) ----
__global__ void scanB_k(const int* __restrict__ bcur, int* __restrict__ sOffs) {
    __shared__ int s[128];
    int t = threadIdx.x;
    int c = (t < NB) ? (bcur[t] - t * CAP) : 0;
    s[t] = c;
    __syncthreads();
    #pragma unroll
    for (int d = 1; d < 128; d <<= 1) {
        int v = (t >= d) ? s[t - d] : 0;
        __syncthreads();
        s[t] += v;
        __syncthreads();
    }
    if (t < NB) sOffs[t] = s[t] - c;   // exclusive
}

// ---- binB2: per bucket, LDS degree-histogram + scan -> offs, then sort -> csrc ----
__global__ __launch_bounds__(256) void binB2_k(const uint_t* __restrict__ ebuf,
                                               const int* __restrict__ bcur,
                                               const int* __restrict__ sOffs,
                                               int* __restrict__ offs,
                                               ushort_t* __restrict__ csrc) {
    __shared__ uint_t eLDS[CAP];
    __shared__ int lhist[512];
    __shared__ int lpre[512];
    __shared__ ushort_t lsrc[CAP];
    int b = blockIdx.x;
    int t = threadIdx.x;
    int n0 = b << BSH;
    int cntE = bcur[b] - b * CAP;
    int obase = sOffs[b];

    for (int i = t; i < 512; i += 256) lhist[i] = 0;
    __syncthreads();
    for (int i = t; i < cntE; i += 256) {
        uint_t pk = ebuf[b * CAP + i];
        eLDS[i] = pk;
        atomicAdd(&lhist[(int)(pk >> 16) - n0], 1);
    }
    __syncthreads();
    // exclusive scan of lhist[512]: pair-reduce -> H-S over 256 -> expand
    int h0 = lhist[2 * t], h1 = lhist[2 * t + 1];
    int pairv = h0 + h1;
    lpre[t] = pairv;
    __syncthreads();
    #pragma unroll
    for (int d = 1; d < 256; d <<= 1) {
        int v = (t >= d) ? lpre[t - d] : 0;
        __syncthreads();
        lpre[t] += v;
        __syncthreads();
    }
    int excl = lpre[t] - pairv;
    __syncthreads();
    lpre[2 * t] = excl;
    lpre[2 * t + 1] = excl + h0;
    __syncthreads();
    // write offs for this bucket's nodes
    for (int i = t; i < 512; i += 256) {
        int node = n0 + i;
        if (node < N_NODES) offs[node] = obase + lpre[i];
    }
    if (b == NB - 1 && t == 0) offs[N_NODES] = N_EDGES;
    // scatter to per-node order (reuse lhist as cursors)
    for (int i = t; i < 512; i += 256) lhist[i] = lpre[i];
    __syncthreads();
    for (int i = t; i < cntE; i += 256) {
        uint_t pk = eLDS[i];
        int p = atomicAdd(&lhist[(int)(pk >> 16) - n0], 1);
        lsrc[p] = (ushort_t)(pk & 0xffffu);
    }
    __syncthreads();
    for (int i = t; i < cntE; i += 256) csrc[obase + i] = lsrc[i];
}

// ---------------- GEMM (r10 config: B-slice regs, persistent, NO dbuf) ----------------
template <int K, int NOUT, int NCB, int PF, bool F32A, int BPG>
__global__ __launch_bounds__(256, 2) void gemm_k(
    const void* __restrict__ Av, const ushort_t* __restrict__ Bp,
    unsigned char* __restrict__ Pout, ushort_t* __restrict__ Rout, int nvalid) {
    constexpr int KT = K / 32;
    constexpr int CTW = NCB / 64;
    constexpr int NCG = NOUT / NCB;
    constexpr int RS = NOUT - PF;
    constexpr int PADE = K + 8;
    constexpr int NTILES = MP / 32;
    constexpr int NWR = K / 64;
    __shared__ ushort_t Atile[32 * PADE];

    int cg = (NCG > 1) ? ((int)blockIdx.x % NCG) : 0;
    int bid = (NCG > 1) ? ((int)blockIdx.x / NCG) : (int)blockIdx.x;
    int wave = threadIdx.x >> 6;
    int lane = threadIdx.x & 63;
    int ct0 = cg * (NCB / 16) + wave * CTW;

    bf16x8 breg[KT][CTW];
    #pragma unroll
    for (int kt = 0; kt < KT; ++kt)
        #pragma unroll
        for (int ct = 0; ct < CTW; ++ct)
            breg[kt][ct] = *reinterpret_cast<const bf16x8*>(
                Bp + ((size_t)(kt * (NOUT / 16) + ct0 + ct) * 64 + lane) * 8);

    int arowoff = lane & 15;
    int r0 = (lane >> 4) * 4;
    int srow = threadIdx.x >> 3;
    int sel = (threadIdx.x & 7) * (K / 8);

    for (int t = bid; t < NTILES; t += BPG) {
        int rowBase = t * 32;
        __syncthreads();
        {
            int grow = min(rowBase + srow, nvalid - 1);
            ushort_t* dst = &Atile[srow * PADE + sel];
            if (F32A) {
                const float* A = (const float*)Av + (size_t)grow * K + sel;
                #pragma unroll
                for (int i = 0; i < NWR; ++i) {
                    float4 f0 = *reinterpret_cast<const float4*>(A + i * 8);
                    float4 f1 = *reinterpret_cast<const float4*>(A + i * 8 + 4);
                    uint4 w;
                    w.x = pk_hi(f0.x, f0.y);
                    w.y = pk_hi(f0.z, f0.w);
                    w.z = pk_hi(f1.x, f1.y);
                    w.w = pk_hi(f1.z, f1.w);
                    *reinterpret_cast<uint4*>(dst + i * 8) = w;
                }
            } else {
                const ushort_t* A = (const ushort_t*)Av + (size_t)grow * K + sel;
                #pragma unroll
                for (int i = 0; i < NWR; ++i)
                    *reinterpret_cast<uint4*>(dst + i * 8) =
                        *reinterpret_cast<const uint4*>(A + i * 8);
            }
        }
        __syncthreads();

        f32x4 acc[2][CTW];
        #pragma unroll
        for (int r = 0; r < 2; ++r)
            #pragma unroll
            for (int c = 0; c < CTW; ++c) acc[r][c] = (f32x4){0.f, 0.f, 0.f, 0.f};

        const ushort_t* A0 = &Atile[arowoff * PADE + (lane >> 4) * 8];
        #pragma unroll
        for (int kt = 0; kt < KT; ++kt) {
            bf16x8 x0 = *reinterpret_cast<const bf16x8*>(A0 + kt * 32);
            bf16x8 x1 = *reinterpret_cast<const bf16x8*>(A0 + 16 * PADE + kt * 32);
            #pragma unroll
            for (int ct = 0; ct < CTW; ++ct) {
                acc[0][ct] = __builtin_amdgcn_mfma_f32_16x16x32_bf16(breg[kt][ct], x0, acc[0][ct], 0, 0, 0);
                acc[1][ct] = __builtin_amdgcn_mfma_f32_16x16x32_bf16(breg[kt][ct], x1, acc[1][ct], 0, 0, 0);
            }
        }

        #pragma unroll
        for (int r = 0; r < 2; ++r) {
            int xrow = rowBase + r * 16 + arowoff;
            #pragma unroll
            for (int ct = 0; ct < CTW; ++ct) {
                int wc = (ct0 + ct) * 16 + r0;
                f32x4 v = acc[r][ct];
                if (PF > 0 && wc < PF) {
                    uint_t u = __builtin_amdgcn_cvt_pk_fp8_f32(v[0], v[1], 0u, false);
                    u = __builtin_amdgcn_cvt_pk_fp8_f32(v[2], v[3], u, true);
                    *reinterpret_cast<uint_t*>(Pout + (size_t)xrow * PF + wc) = u;
                } else {
                    uint2 w;
                    w.x = (uint_t)f2bf(v[0]) | ((uint_t)f2bf(v[1]) << 16);
                    w.y = (uint_t)f2bf(v[2]) | ((uint_t)f2bf(v[3]) << 16);
                    *reinterpret_cast<uint2*>(Rout + (size_t)xrow * RS + (wc - PF)) = w;
                }
            }
        }
    }
}

// ---------------- fused aggregate (fp8 P) + epilogue, 2 nodes/wave ----------------
template <int F, bool FINAL>
__global__ __launch_bounds__(256) void aggP8_k(
    const unsigned char* __restrict__ P, const int* __restrict__ offs,
    const ushort_t* __restrict__ csrc, const ushort_t* __restrict__ R,
    const float* __restrict__ bias, ushort_t* __restrict__ H,
    float* __restrict__ hout, float* __restrict__ lout, int n) {
    constexpr int LPG = F / 8;
    constexpr int G = 64 / LPG;
    constexpr int U = (G >= 4) ? 1 : (4 / G);
    constexpr int ST = G * U;
    int wid = (blockIdx.x * 256 + threadIdx.x) >> 6;
    int lane = threadIdx.x & 63;
    int g = lane / LPG;
    int sub = lane & (LPG - 1);
    int colbase = sub * 8;
    int n0 = 2 * wid, n1 = 2 * wid + 1;
    if (n0 >= n) return;
    bool has1 = (n1 < n);
    int b0 = offs[n0], end0 = offs[n0 + 1];
    int b1 = has1 ? offs[n1] : 0, end1 = has1 ? offs[n1 + 1] : 0;

    float a0[8] = {0,0,0,0,0,0,0,0};
    float a1[8] = {0,0,0,0,0,0,0,0};
    int e0 = b0, e1 = b1;
    const unsigned char* Pc = P + colbase;

    while (e0 + ST <= end0 && e1 + ST <= end1) {
        uint2 d0[U], d1[U];
        #pragma unroll
        for (int u = 0; u < U; ++u) {
            int s = csrc[e0 + g + u * G];
            d0[u] = *reinterpret_cast<const uint2*>(Pc + (size_t)s * F);
        }
        #pragma unroll
        for (int u = 0; u < U; ++u) {
            int s = csrc[e1 + g + u * G];
            d1[u] = *reinterpret_cast<const uint2*>(Pc + (size_t)s * F);
        }
        #pragma unroll
        for (int u = 0; u < U; ++u) { accf8(a0, d0[u]); accf8(a1, d1[u]); }
        e0 += ST; e1 += ST;
    }
    while (e0 + ST <= end0) {
        uint2 d[U];
        #pragma unroll
        for (int u = 0; u < U; ++u) {
            int s = csrc[e0 + g + u * G];
            d[u] = *reinterpret_cast<const uint2*>(Pc + (size_t)s * F);
        }
        #pragma unroll
        for (int u = 0; u < U; ++u) accf8(a0, d[u]);
        e0 += ST;
    }
    for (int e = e0 + g; e < end0; e += G) {
        int s = csrc[e];
        uint2 d = *reinterpret_cast<const uint2*>(Pc + (size_t)s * F);
        accf8(a0, d);
    }
    while (e1 + ST <= end1) {
        uint2 d[U];
        #pragma unroll
        for (int u = 0; u < U; ++u) {
            int s = csrc[e1 + g + u * G];
            d[u] = *reinterpret_cast<const uint2*>(Pc + (size_t)s * F);
        }
        #pragma unroll
        for (int u = 0; u < U; ++u) accf8(a1, d[u]);
        e1 += ST;
    }
    for (int e = e1 + g; e < end1; e += G) {
        int s = csrc[e];
        uint2 d = *reinterpret_cast<const uint2*>(Pc + (size_t)s * F);
        accf8(a1, d);
    }

    #pragma unroll
    for (int off = LPG; off < 64; off <<= 1) {
        #pragma unroll
        for (int i = 0; i < 8; ++i) {
            a0[i] += __shfl_xor(a0[i], off);
            a1[i] += __shfl_xor(a1[i], off);
        }
    }

    float inv0 = 1.f / fmaxf((float)(end0 - b0), 1.f);
    float inv1 = 1.f / fmaxf((float)(end1 - b1), 1.f);

    #pragma unroll
    for (int j = 0; j < 2; ++j) {
        if (j && !has1) break;
        int node = j ? n1 : n0;
        float* a = j ? a1 : a0;
        float inv = j ? inv1 : inv0;
        uint4 rr = *reinterpret_cast<const uint4*>(R + (size_t)node * F + colbase);
        float r[8];
        r[0] = bf2f(rr.x & 0xffff); r[1] = bf2f(rr.x >> 16);
        r[2] = bf2f(rr.y & 0xffff); r[3] = bf2f(rr.y >> 16);
        r[4] = bf2f(rr.z & 0xffff); r[5] = bf2f(rr.z >> 16);
        r[6] = bf2f(rr.w & 0xffff); r[7] = bf2f(rr.w >> 16);
        float4 bA = *reinterpret_cast<const float4*>(bias + colbase);
        float4 bB = *reinterpret_cast<const float4*>(bias + colbase + 4);
        float bv[8] = {bA.x, bA.y, bA.z, bA.w, bB.x, bB.y, bB.z, bB.w};
        float v[8];
        #pragma unroll
        for (int i = 0; i < 8; ++i) v[i] = a[i] * inv + r[i] + bv[i];

        if constexpr (!FINAL) {
            if (lane < LPG) {
                uint_t w[4];
                #pragma unroll
                for (int p = 0; p < 4; ++p) {
                    float v0 = fmaxf(v[2 * p], 0.f);
                    float v1 = fmaxf(v[2 * p + 1], 0.f);
                    w[p] = (uint_t)f2bf(v0) | ((uint_t)f2bf(v1) << 16);
                }
                *reinterpret_cast<uint4*>(H + (size_t)node * F + colbase) =
                    make_uint4(w[0], w[1], w[2], w[3]);
            }
        } else {
            float m = v[0];
            #pragma unroll
            for (int i = 1; i < 8; ++i) m = fmaxf(m, v[i]);
            #pragma unroll
            for (int off = 1; off < LPG; off <<= 1) m = fmaxf(m, __shfl_xor(m, off));
            float s = 0.f;
            #pragma unroll
            for (int i = 0; i < 8; ++i) s += expf(v[i] - m);
            #pragma unroll
            for (int off = 1; off < LPG; off <<= 1) s += __shfl_xor(s, off);
            float ls = m + logf(s);
            if (lane < LPG) {
                float* ho = hout + (size_t)node * 64 + colbase;
                float* lo = lout + (size_t)node * 64 + colbase;
                *reinterpret_cast<float4*>(ho) = make_float4(v[0], v[1], v[2], v[3]);
                *reinterpret_cast<float4*>(ho + 4) = make_float4(v[4], v[5], v[6], v[7]);
                *reinterpret_cast<float4*>(lo) =
                    make_float4(v[0] - ls, v[1] - ls, v[2] - ls, v[3] - ls);
                *reinterpret_cast<float4*>(lo + 4) =
                    make_float4(v[4] - ls, v[5] - ls, v[6] - ls, v[7] - ls);
            }
        }
    }
}

extern "C" void kernel_launch(void* const* d_in, const int* in_sizes, int n_in,
                              void* d_out, int out_size, void* d_ws, size_t ws_size,
                              hipStream_t stream) {
    const float* x   = (const float*)d_in[0];
    const int*   ei  = (const int*)d_in[1];
    const float* W1l = (const float*)d_in[2];
    const float* b1  = (const float*)d_in[3];
    const float* W1r = (const float*)d_in[4];
    const float* W2l = (const float*)d_in[5];
    const float* b2  = (const float*)d_in[6];
    const float* W2r = (const float*)d_in[7];
    const float* W3l = (const float*)d_in[8];
    const float* b3  = (const float*)d_in[9];
    const float* W3r = (const float*)d_in[10];
    const int* esrc = ei;
    const int* edst = ei + N_EDGES;

    char* ws = (char*)d_ws;
    size_t off = 0;
    auto alloc = [&](size_t b) { void* p = ws + off; off = (off + b + 255) & ~(size_t)255; return p; };
    unsigned char* P1 = (unsigned char*)alloc((size_t)MP * 256);  // fp8; reused as P2/P3
    ushort_t* R1 = (ushort_t*)alloc((size_t)MP * 256 * 2);        // bf16; reused as R2/R3
    ushort_t* H1 = (ushort_t*)alloc((size_t)MP * 256 * 2);
    ushort_t* H2 = (ushort_t*)alloc((size_t)MP * 128 * 2);
    int* offs = (int*)alloc((N_NODES + 1) * 4);
    int* bcur = (int*)alloc(NB * 4);
    int* sOffs = (int*)alloc(NB * 4);
    ushort_t* csrc = (ushort_t*)alloc(N_EDGES * 2);
    uint_t* ebuf = (uint_t*)alloc((size_t)NB * CAP * 4);
    ushort_t* pB1 = (ushort_t*)alloc(256 * 512 * 2);
    ushort_t* pB2 = (ushort_t*)alloc(256 * 256 * 2);
    ushort_t* pB3 = (ushort_t*)alloc(128 * 128 * 2);

    unsigned char* P2 = P1;
    ushort_t* R2 = R1;
    unsigned char* P3 = P1;
    ushort_t* R3 = R1;

    // pack weights + init bucket cursors (no memset dispatch)
    pack_all_k<<<(26624 + NB + 255) / 256, 256, 0, stream>>>(
        W1l, W1r, W2l, W2r, W3l, W3r, pB1, pB2, pB3, bcur);

    // CSR build: bin -> tiny bucket scan -> per-bucket LDS degree+sort
    binA_k<<<(N_EDGES + 2047) / 2048, 256, 0, stream>>>(esrc, edst, bcur, ebuf, N_EDGES);
    scanB_k<<<1, 128, 0, stream>>>(bcur, sOffs);
    binB2_k<<<NB, 256, 0, stream>>>(ebuf, bcur, sOffs, offs, csrc);

    constexpr int BPG = 512;
    int aggGrid = ((N_NODES + 1) / 2 + 3) / 4; // 6250
    float* hout = (float*)d_out;
    float* lout = hout + (size_t)N_NODES * 64;

    // layer 1: P1(fp8)|R1(bf16) = x(f32) @ [W1l|W1r]; h1 = relu(mean(P1)+R1+b1)
    gemm_k<256, 512, 256, 256, true, BPG><<<2 * BPG, 256, 0, stream>>>(x, pB1, P1, R1, N_NODES);
    aggP8_k<256, false><<<aggGrid, 256, 0, stream>>>(
        P1, offs, csrc, R1, b1, H1, nullptr, nullptr, N_NODES);
    // layer 2
    gemm_k<256, 256, 256, 128, false, BPG><<<BPG, 256, 0, stream>>>(H1, pB2, P2, R2, N_NODES);
    aggP8_k<128, false><<<aggGrid, 256, 0, stream>>>(
        P2, offs, csrc, R2, b2, H2, nullptr, nullptr, N_NODES);
    // layer 3: P3(fp8)|R3(bf16) = H2 @ [W3l|W3r]; fused mean+bias+log_softmax
    gemm_k<128, 128, 128, 64, false, BPG><<<BPG, 256, 0, stream>>>(H2, pB3, P3, R3, N_NODES);
    aggP8_k<64, true><<<aggGrid, 256, 0, stream>>>(
        P3, offs, csrc, R3, b3, nullptr, hout, lout, N_NODES);
}